// Round 1
// baseline (726.557 us; speedup 1.0000x reference)
//
#include <hip/hip_runtime.h>
#include <math.h>

#define BB 64
#define SS 4096
#define DXX 512
#define QQ 128
#define DQQ 512
#define SPLITS 16
#define CHUNK (SS / SPLITS)          // 256 rows per block
#define NWAVES 4
#define ROWS_PER_WAVE (CHUNK / NWAVES) // 64

// ---------------------------------------------------------------------------
// Kernel 1: first[b,:] = (sum_q p[q]*query[b,q,:]) @ W        [B, DX]
// 64 blocks x 512 threads. query reads coalesced over dq; W coalesced over dx.
// ---------------------------------------------------------------------------
__global__ __launch_bounds__(512) void compute_first(
        const float* __restrict__ qm, const float* __restrict__ W,
        const float* __restrict__ p, float* __restrict__ first) {
    int b = blockIdx.x;
    int t = threadIdx.x;                    // 0..511
    __shared__ float sp[QQ];
    __shared__ float snq[DQQ];
    if (t < QQ) sp[t] = p[t];
    __syncthreads();

    // new_q[b, t] = sum_q query[b,q,t] * p[q]
    const float* qb = qm + (size_t)b * QQ * DQQ + t;
    float acc = 0.f;
    #pragma unroll 8
    for (int q = 0; q < QQ; ++q) acc = fmaf(qb[(size_t)q * DQQ], sp[q], acc);
    snq[t] = acc;
    __syncthreads();

    // first[b, t] = sum_dq new_q[dq] * W[dq, t]
    float f = 0.f;
    #pragma unroll 8
    for (int dq = 0; dq < DQQ; ++dq) f = fmaf(snq[dq], W[(size_t)dq * DXX + t], f);
    first[b * DXX + t] = f;
}

// ---------------------------------------------------------------------------
// Kernel 2: flash-style single pass over x. One wave per s-row; each lane
// holds 8 dx (f and acc in registers). Online softmax per wave; block merges
// its 4 waves in LDS and writes one partial (m, l, acc[512]) per block.
// Grid: B*SPLITS blocks x 256 threads.
// ---------------------------------------------------------------------------
__global__ __launch_bounds__(256) void attn_partial(
        const float* __restrict__ x, const float* __restrict__ first,
        float* __restrict__ pm, float* __restrict__ pl,
        float* __restrict__ pacc) {
    int blk  = blockIdx.x;
    int b    = blk / SPLITS;
    int sp   = blk % SPLITS;
    int tid  = threadIdx.x;
    int wave = tid >> 6;
    int lane = tid & 63;

    // f fragment: dx = lane*4+j  and  256 + lane*4+j  (perfectly coalesced)
    const float* fb = first + b * DXX;
    const float4 f0 = *(const float4*)(fb + lane * 4);
    const float4 f1 = *(const float4*)(fb + 256 + lane * 4);

    float m = -1e30f, l = 0.f;
    float4 a0 = {0.f, 0.f, 0.f, 0.f};
    float4 a1 = {0.f, 0.f, 0.f, 0.f};

    const float* xb = x + (size_t)b * SS * DXX;
    const int s0 = sp * CHUNK + wave;       // waves interleave rows: wave stride 4

    #pragma unroll 2
    for (int i = 0; i < ROWS_PER_WAVE; ++i) {
        const int s = s0 + i * NWAVES;
        const float* xr = xb + (size_t)s * DXX;
        const float4 x0 = *(const float4*)(xr + lane * 4);
        const float4 x1 = *(const float4*)(xr + 256 + lane * 4);

        float d = f0.x * x0.x + f0.y * x0.y + f0.z * x0.z + f0.w * x0.w
                + f1.x * x1.x + f1.y * x1.y + f1.z * x1.z + f1.w * x1.w;
        // 64-lane butterfly reduce -> every lane holds the full dot product
        #pragma unroll
        for (int off = 32; off > 0; off >>= 1) d += __shfl_xor(d, off, 64);

        const float nm    = fmaxf(m, d);
        const float alpha = __expf(m - nm);   // rescale old state
        const float w     = __expf(d - nm);   // weight of this row
        l = l * alpha + w;
        a0.x = fmaf(a0.x, alpha, w * x0.x);
        a0.y = fmaf(a0.y, alpha, w * x0.y);
        a0.z = fmaf(a0.z, alpha, w * x0.z);
        a0.w = fmaf(a0.w, alpha, w * x0.w);
        a1.x = fmaf(a1.x, alpha, w * x1.x);
        a1.y = fmaf(a1.y, alpha, w * x1.y);
        a1.z = fmaf(a1.z, alpha, w * x1.z);
        a1.w = fmaf(a1.w, alpha, w * x1.w);
        m = nm;
    }

    // merge the 4 waves of this block in LDS
    __shared__ float sm[NWAVES];
    __shared__ float sl[NWAVES];
    __shared__ float sacc[NWAVES][DXX];     // 8 KiB
    if (lane == 0) { sm[wave] = m; sl[wave] = l; }
    float* sa = sacc[wave];
    *(float4*)(sa + lane * 4)       = a0;
    *(float4*)(sa + 256 + lane * 4) = a1;
    __syncthreads();

    const float M  = fmaxf(fmaxf(sm[0], sm[1]), fmaxf(sm[2], sm[3]));
    const float e0 = __expf(sm[0] - M), e1 = __expf(sm[1] - M);
    const float e2 = __expf(sm[2] - M), e3 = __expf(sm[3] - M);
    if (tid == 0) {
        pm[blk] = M;
        pl[blk] = sl[0] * e0 + sl[1] * e1 + sl[2] * e2 + sl[3] * e3;
    }
    #pragma unroll
    for (int dx = tid; dx < DXX; dx += 256) {
        pacc[(size_t)blk * DXX + dx] =
            sacc[0][dx] * e0 + sacc[1][dx] * e1 + sacc[2][dx] * e2 + sacc[3][dx] * e3;
    }
}

// ---------------------------------------------------------------------------
// Kernel 3: merge the SPLITS partials per batch and normalize.
// Grid: B blocks x 256 threads.
// ---------------------------------------------------------------------------
__global__ __launch_bounds__(256) void attn_finalize(
        const float* __restrict__ pm, const float* __restrict__ pl,
        const float* __restrict__ pacc, float* __restrict__ out) {
    int b = blockIdx.x;
    int tid = threadIdx.x;

    __shared__ float e[SPLITS];
    __shared__ float invL;
    if (tid == 0) {
        float M = -1e30f;
        for (int i = 0; i < SPLITS; ++i) M = fmaxf(M, pm[b * SPLITS + i]);
        float L = 0.f;
        for (int i = 0; i < SPLITS; ++i) {
            float ei = __expf(pm[b * SPLITS + i] - M);
            e[i] = ei;
            L += pl[b * SPLITS + i] * ei;
        }
        invL = 1.f / L;
    }
    __syncthreads();

    #pragma unroll
    for (int dx = tid; dx < DXX; dx += 256) {
        float v = 0.f;
        for (int i = 0; i < SPLITS; ++i)
            v = fmaf(pacc[(size_t)(b * SPLITS + i) * DXX + dx], e[i], v);
        out[b * DXX + dx] = v * invL;
    }
}

// ---------------------------------------------------------------------------
extern "C" void kernel_launch(void* const* d_in, const int* in_sizes, int n_in,
                              void* d_out, int out_size, void* d_ws, size_t ws_size,
                              hipStream_t stream) {
    const float* x  = (const float*)d_in[0];  // [B,S,DX]
    const float* qm = (const float*)d_in[1];  // [B,Q,DQ]
    const float* W  = (const float*)d_in[2];  // [DQ,DX]
    const float* p  = (const float*)d_in[3];  // [Q,1]
    float* out = (float*)d_out;               // [B,DX]

    float* ws    = (float*)d_ws;
    float* first = ws;                        // B*DX          = 32768 floats
    float* pm    = first + BB * DXX;          // B*SPLITS      = 1024
    float* pl    = pm + BB * SPLITS;          // B*SPLITS      = 1024
    float* pacc  = pl + BB * SPLITS;          // B*SPLITS*DX   = 524288 floats
    // total ~2.25 MB of workspace

    compute_first<<<BB, 512, 0, stream>>>(qm, W, p, first);
    attn_partial<<<BB * SPLITS, 256, 0, stream>>>(x, first, pm, pl, pacc);
    attn_finalize<<<BB, 256, 0, stream>>>(pm, pl, pacc, out);
}

// Round 2
// 703.318 us; speedup vs baseline: 1.0330x; 1.0330x over previous
//
#include <hip/hip_runtime.h>
#include <math.h>

#define BB 64
#define SS 4096
#define DXX 512
#define QQ 128
#define DQQ 512
#define SPLITS 32
#define CHUNK (SS / SPLITS)            // 128 rows per block
#define NWAVES 4
#define ROWS_PER_WAVE (CHUNK / NWAVES) // 32
#define RB 4                           // rows per batch (interleaved reduce chains)

typedef float v4 __attribute__((ext_vector_type(4)));

// ---------------------------------------------------------------------------
// Kernel 1: first[b,:] = (sum_q p[q]*query[b,q,:]) @ W        [B, DX]
// ---------------------------------------------------------------------------
__global__ __launch_bounds__(512) void compute_first(
        const float* __restrict__ qm, const float* __restrict__ W,
        const float* __restrict__ p, float* __restrict__ first) {
    int b = blockIdx.x;
    int t = threadIdx.x;                    // 0..511
    __shared__ float sp[QQ];
    __shared__ float snq[DQQ];
    if (t < QQ) sp[t] = p[t];
    __syncthreads();

    const float* qb = qm + (size_t)b * QQ * DQQ + t;
    float acc = 0.f;
    #pragma unroll 8
    for (int q = 0; q < QQ; ++q) acc = fmaf(qb[(size_t)q * DQQ], sp[q], acc);
    snq[t] = acc;
    __syncthreads();

    float f = 0.f;
    #pragma unroll 8
    for (int dq = 0; dq < DQQ; ++dq) f = fmaf(snq[dq], W[(size_t)dq * DXX + t], f);
    first[b * DXX + t] = f;
}

// ---------------------------------------------------------------------------
// Kernel 2: flash-style single pass over x. One wave per s-row, 4 rows per
// batch so the 4 butterfly-reduce chains interleave. Online softmax with a
// wave-uniform fast path (max rarely updates: scores ~ N(0, 5800)).
// Grid: B*SPLITS = 2048 blocks x 256 threads -> 8 blocks/CU, 32 waves/CU.
// ---------------------------------------------------------------------------
__global__ __launch_bounds__(256) void attn_partial(
        const float* __restrict__ x, const float* __restrict__ first,
        float* __restrict__ pm, float* __restrict__ pl,
        float* __restrict__ pacc) {
    int blk  = blockIdx.x;
    int b    = blk / SPLITS;
    int sp   = blk % SPLITS;
    int tid  = threadIdx.x;
    int wave = tid >> 6;
    int lane = tid & 63;

    const float* fb = first + b * DXX;
    const v4 f0 = *(const v4*)(fb + lane * 4);
    const v4 f1 = *(const v4*)(fb + 256 + lane * 4);

    float m = -1e30f, l = 0.f;
    v4 a0 = {0.f, 0.f, 0.f, 0.f};
    v4 a1 = {0.f, 0.f, 0.f, 0.f};

    const float* xb = x + (size_t)b * SS * DXX;
    const int s0 = sp * CHUNK + wave;       // waves interleave rows, stride 4

    for (int i = 0; i < ROWS_PER_WAVE; i += RB) {
        v4 x0[RB], x1[RB];
        float d[RB];
        #pragma unroll
        for (int r = 0; r < RB; ++r) {
            const float* xr = xb + (size_t)(s0 + (i + r) * NWAVES) * DXX;
            x0[r] = __builtin_nontemporal_load((const v4*)(xr + lane * 4));
            x1[r] = __builtin_nontemporal_load((const v4*)(xr + 256 + lane * 4));
            v4 t4 = f0 * x0[r] + f1 * x1[r];
            d[r] = t4.x + t4.y + t4.z + t4.w;
        }
        // 4 interleaved 64-lane butterflies; all lanes end bit-identical
        #pragma unroll
        for (int off = 32; off > 0; off >>= 1) {
            #pragma unroll
            for (int r = 0; r < RB; ++r) d[r] += __shfl_xor(d[r], off, 64);
        }
        #pragma unroll
        for (int r = 0; r < RB; ++r) {
            if (d[r] > m) {                 // wave-uniform: rare rescale path
                const float alpha = __expf(m - d[r]);
                m = d[r];
                l = fmaf(l, alpha, 1.f);
                a0 = a0 * alpha + x0[r];
                a1 = a1 * alpha + x1[r];
            } else {                        // common path: no rescale
                const float w = __expf(d[r] - m);
                l += w;
                a0 += x0[r] * w;
                a1 += x1[r] * w;
            }
        }
    }

    // merge the 4 waves of this block in LDS
    __shared__ float sm[NWAVES];
    __shared__ float sl[NWAVES];
    __shared__ float sacc[NWAVES][DXX];     // 8 KiB
    if (lane == 0) { sm[wave] = m; sl[wave] = l; }
    float* sa = sacc[wave];
    *(v4*)(sa + lane * 4)       = a0;
    *(v4*)(sa + 256 + lane * 4) = a1;
    __syncthreads();

    const float M  = fmaxf(fmaxf(sm[0], sm[1]), fmaxf(sm[2], sm[3]));
    const float e0 = __expf(sm[0] - M), e1 = __expf(sm[1] - M);
    const float e2 = __expf(sm[2] - M), e3 = __expf(sm[3] - M);
    if (tid == 0) {
        pm[blk] = M;
        pl[blk] = sl[0] * e0 + sl[1] * e1 + sl[2] * e2 + sl[3] * e3;
    }
    #pragma unroll
    for (int dx = tid; dx < DXX; dx += 256) {
        pacc[(size_t)blk * DXX + dx] =
            sacc[0][dx] * e0 + sacc[1][dx] * e1 + sacc[2][dx] * e2 + sacc[3][dx] * e3;
    }
}

// ---------------------------------------------------------------------------
// Kernel 3: merge the SPLITS partials per batch and normalize.
// ---------------------------------------------------------------------------
__global__ __launch_bounds__(256) void attn_finalize(
        const float* __restrict__ pm, const float* __restrict__ pl,
        const float* __restrict__ pacc, float* __restrict__ out) {
    int b = blockIdx.x;
    int tid = threadIdx.x;

    __shared__ float e[SPLITS];
    __shared__ float invL;
    if (tid == 0) {
        float M = -1e30f;
        for (int i = 0; i < SPLITS; ++i) M = fmaxf(M, pm[b * SPLITS + i]);
        float L = 0.f;
        for (int i = 0; i < SPLITS; ++i) {
            float ei = __expf(pm[b * SPLITS + i] - M);
            e[i] = ei;
            L += pl[b * SPLITS + i] * ei;
        }
        invL = 1.f / L;
    }
    __syncthreads();

    #pragma unroll
    for (int dx = tid; dx < DXX; dx += 256) {
        float v = 0.f;
        for (int i = 0; i < SPLITS; ++i)
            v = fmaf(pacc[(size_t)(b * SPLITS + i) * DXX + dx], e[i], v);
        out[b * DXX + dx] = v * invL;
    }
}

// ---------------------------------------------------------------------------
extern "C" void kernel_launch(void* const* d_in, const int* in_sizes, int n_in,
                              void* d_out, int out_size, void* d_ws, size_t ws_size,
                              hipStream_t stream) {
    const float* x  = (const float*)d_in[0];  // [B,S,DX]
    const float* qm = (const float*)d_in[1];  // [B,Q,DQ]
    const float* W  = (const float*)d_in[2];  // [DQ,DX]
    const float* p  = (const float*)d_in[3];  // [Q,1]
    float* out = (float*)d_out;               // [B,DX]

    float* ws    = (float*)d_ws;
    float* first = ws;                        // B*DX          = 32768 floats
    float* pm    = first + BB * DXX;          // B*SPLITS      = 2048
    float* pl    = pm + BB * SPLITS;          // B*SPLITS      = 2048
    float* pacc  = pl + BB * SPLITS;          // B*SPLITS*DX   = 1048576 floats (4 MB)

    compute_first<<<BB, 512, 0, stream>>>(qm, W, p, first);
    attn_partial<<<BB * SPLITS, 256, 0, stream>>>(x, first, pm, pl, pacc);
    attn_finalize<<<BB, 256, 0, stream>>>(pm, pl, pacc, out);
}